// Round 12
// baseline (23.110 us; speedup 1.0000x reference)
//
#include <hip/hip_runtime.h>
#include <hip/hip_bf16.h>
#include <math.h>

#define OUT_LEN 512
#define T_IN    2048
#define C_CH    64
#define BN      32
#define NTT     (OUT_LEN / BN)   // 16 tau-tiles
#define KSPLIT  8

typedef __attribute__((ext_vector_type(8))) short bf16x8;
typedef __attribute__((ext_vector_type(4))) float f32x4;

static __device__ __forceinline__ short f2bf(float f) {
    unsigned int u = __float_as_uint(f);
    unsigned int r = (u + 0x7FFFu + ((u >> 16) & 1u)) >> 16;   // RNE
    return (short)r;
}

// ---------------------------------------------------------------------------
// K0: fused prep.
//  - convert x (f32) -> xbf (bf16), 8 elems/thread
//  - init out: zeros for L>=512 batches (atomic base), masked copy for L<512
// ---------------------------------------------------------------------------
__global__ __launch_bounds__(256) void prep_kernel(
    const float* __restrict__ x, const int* __restrict__ length,
    unsigned short* __restrict__ xbf, float* __restrict__ out, int B)
{
    const int idx = blockIdx.x * 256 + threadIdx.x;
    const int total8 = B * C_CH * T_IN / 8;
    if (idx < total8) {
        const float4 v0 = ((const float4*)x)[2 * idx];
        const float4 v1 = ((const float4*)x)[2 * idx + 1];
        union { short s[8]; int4 v; } pk;
        pk.s[0] = f2bf(v0.x); pk.s[1] = f2bf(v0.y);
        pk.s[2] = f2bf(v0.z); pk.s[3] = f2bf(v0.w);
        pk.s[4] = f2bf(v1.x); pk.s[5] = f2bf(v1.y);
        pk.s[6] = f2bf(v1.z); pk.s[7] = f2bf(v1.w);
        ((int4*)xbf)[idx] = pk.v;
    }
    const int outq = B * C_CH * (OUT_LEN / 4);
    if (idx < outq) {
        const int b = idx >> 13;                    // 8192 float4 per batch
        const int L = length[b];
        float4 o = {0.f, 0.f, 0.f, 0.f};
        if (L < OUT_LEN) {
            const int t4 = idx & (OUT_LEN / 4 - 1);
            const int c  = (idx >> 7) & (C_CH - 1);
            const int t  = t4 * 4;
            const float4 v = *(const float4*)(x + ((size_t)b * C_CH + c) * T_IN + t);
            o.x = (t + 0 < L) ? v.x : 0.0f;
            o.y = (t + 1 < L) ? v.y : 0.0f;
            o.z = (t + 2 < L) ? v.z : 0.0f;
            o.w = (t + 3 < L) ? v.w : 0.0f;
        }
        ((float4*)out)[idx] = o;
    }
}

// ---------------------------------------------------------------------------
// K1: GEMM with on-the-fly M, atomic accumulation into out (r6 structure,
// KSPLIT=8 for full occupancy: 2048 blocks = 8/CU = 32 waves/CU).
// M_L[t][tau] = sin(pi*n/L) * cot(pi*n/(512L)) / 512,  n = 512t - tau*L.
// sin term: (-1)^tau * tab[t]; sign folds into cot's argument.
// cot(w) ~ 1/w + w*(-1/3 - w^2/45 - 2w^4/945) after wrap w -= pi*rndne(w/pi).
// A-fragments in registers; B double-buffered in LDS, ONE barrier per iter.
// Grid: bid = (b*NTT + tt)*KSPLIT + h (r6 order, best measured).
// ---------------------------------------------------------------------------
__global__ __launch_bounds__(256) void spectral_gemm(
    const unsigned short* __restrict__ xbf, const int* __restrict__ length,
    float* __restrict__ out, int B)
{
    const int bid = blockIdx.x;
    const int h   = bid & (KSPLIT - 1);
    const int rem = bid >> 3;
    const int tt  = rem % NTT;
    const int b   = rem / NTT;
    const int tid = threadIdx.x;
    const int L   = length[b];
    if (L < OUT_LEN) return;                        // prep wrote the copy branch

    const int tau0 = tt * BN;

    __shared__ short B_lds[2][2][2][64][8];         // [p][j][ksub][lane][i]
    __shared__ float tab[T_IN];

    // ---- tab[t] = sin(2*pi*(256t mod L)/L)/512, 0 for t>=L ----
    {
        const float invLf = 1.0f / (float)L;
        int q = (int)(65536.0f * invLf);
        int d256 = 65536 - q * L;                   // 65536 mod L
        if (d256 < 0)  d256 += L;
        if (d256 >= L) d256 -= L;
        const int v = tid << 8;                     // 256*tid
        q = (int)((float)v * invLf);
        int m = v - q * L;
        if (m < 0)  m += L;
        if (m >= L) m -= L;
        for (int i = tid; i < T_IN; i += 256) {
            tab[i] = (i < L)
                ? __builtin_amdgcn_sinf((float)m * invLf) * 0.001953125f : 0.0f;
            m += d256; if (m >= L) m -= L;
        }
    }

    // ---- A role: global fragment pointer (regs == fragment, no LDS) ----
    const int lane = tid & 63;
    const int wid  = tid >> 6;
    const unsigned short* gsrc =
        xbf + ((size_t)(b * C_CH + wid * 16 + (lane & 15))) * T_IN + ((lane >> 4) * 8);

    // ---- B-build role ----
    const int tau_l = tid & 31;
    const int tauv  = tau0 + tau_l;
    const int tb8   = (tid >> 5) << 3;              // 0,8,...,56
    const int jB    = tau_l >> 4;
    const int gB    = (tb8 >> 3) & 3;
    const int ksubB = tb8 >> 5;
    const int laneB = (tau_l & 15) + (gB << 4);

    const int L256 = L << 8;
    const int L512 = L << 9;
    const float inv512L   = 1.0f / (float)L512;
    const float piInv512L = 3.14159265358979f * inv512L;
    const int sgn = (tauv & 1) ? -1 : 1;
    const int dnc = sgn * (KSPLIT * 64 * 512);      // chunk advance (t += 512)
    const float stpf = (float)(sgn << 9);           // +-512 per t

    // initial n0 = sgn*(512*t_first - tau*L), reduced mod 512L to (-256L, 256L]
    int n0 = sgn * (512 * (h * 64 + tb8) - tauv * L);
    {
        const int q = (int)rintf((float)n0 * inv512L);
        n0 -= q * L512;
        if (n0 <= -L256) n0 += L512;
        if (n0 >   L256) n0 -= L512;
    }

    const int nc = (L + 63) >> 6;                   // 8..32, so h < nc always

    f32x4 acc0 = {0.f, 0.f, 0.f, 0.f};
    f32x4 acc1 = {0.f, 0.f, 0.f, 0.f};

    // prologue A prefetch (issue before tab barrier to hide HBM latency)
    int4 pf0, pf1;
    {
        const unsigned short* g = gsrc + (h << 6);
        pf0 = *(const int4*)(g);
        pf1 = *(const int4*)(g + 32);
    }

    // M-chunk builder: 8 entries/thread into B_lds[pp], advances n0.
    // |dnc| = 262144 <= 512L for L>=512, so the two-sided single-step wrap
    // below keeps n0 in (-256L, 256L] exactly.
    auto BUILD = [&](int pp, int ss) {
        const int t0 = ss << 6;
        float sv0[4], sv1[4];
        *(float4*)sv0 = *(const float4*)&tab[t0 + tb8];       // broadcast b128
        *(float4*)sv1 = *(const float4*)&tab[t0 + tb8 + 4];
        const float n0f = (float)n0;                          // exact (<2^21)
        float Mv[8];
        #pragma unroll
        for (int d = 0; d < 8; ++d) {
            const float nf = fmaf((float)d, stpf, n0f);       // exact
            const float w  = nf * piInv512L;
            const float rW = rintf(w * 0.318309886183790672f);
            const float wp = fmaf(rW, -3.14159265358979f, w); // wrap to (-pi/2,pi/2]
            const float ru = __builtin_amdgcn_rcpf(wp);
            const float w2 = wp * wp;
            const float pq = fmaf(w2, fmaf(w2, -2.1164021e-3f, -2.2222222e-2f),
                                  -0.333333333f);
            const float cotv = fmaf(wp, pq, ru);
            Mv[d] = ((d < 4) ? sv0[d] : sv1[d - 4]) * cotv;
        }
        // rare singular fix: n hits 0 inside this chunk -> true M is 1 (t<L)
        const int negAn = (sgn > 0) ? -n0 : n0;
        if ((unsigned)negAn <= 3584u && (n0 & 511) == 0) {
            const int ds = negAn >> 9;
            const float fix = (t0 + tb8 + ds < L) ? 1.0f : 0.0f;
            #pragma unroll
            for (int d = 0; d < 8; ++d)                        // static idx only
                if (d == ds) Mv[d] = fix;
        }
        union { __hip_bfloat162 h2[4]; int4 v; } pk;
        #pragma unroll
        for (int e = 0; e < 4; ++e)
            pk.h2[e] = __float22bfloat162_rn(make_float2(Mv[2 * e], Mv[2 * e + 1]));
        *(int4*)&B_lds[pp][jB][ksubB][laneB][0] = pk.v;
        n0 += dnc;
        if (n0 >  L256)  n0 -= L512;
        if (n0 <= -L256) n0 += L512;
    };

    __syncthreads();                                // tab visible
    BUILD(0, h);
    int p = 0;

    for (int s = h; s < nc; s += KSPLIT) {
        __syncthreads();                            // publishes B_lds[p]
        const int sn = s + KSPLIT;
        const bool more = (sn < nc);
        int4 nf0 = pf0, nf1 = pf1;
        if (more) {
            const unsigned short* g = gsrc + (sn << 6);
            nf0 = *(const int4*)(g);
            nf1 = *(const int4*)(g + 32);
        }
        const bf16x8 b00 = *(const bf16x8*)&B_lds[p][0][0][lane][0];
        const bf16x8 b01 = *(const bf16x8*)&B_lds[p][0][1][lane][0];
        const bf16x8 b10 = *(const bf16x8*)&B_lds[p][1][0][lane][0];
        const bf16x8 b11 = *(const bf16x8*)&B_lds[p][1][1][lane][0];
        if (more) BUILD(p ^ 1, sn);                 // overlaps MFMA across waves
        const bf16x8 a0 = *(const bf16x8*)&pf0;
        const bf16x8 a1 = *(const bf16x8*)&pf1;
        acc0 = __builtin_amdgcn_mfma_f32_16x16x32_bf16(a0, b00, acc0, 0, 0, 0);
        acc0 = __builtin_amdgcn_mfma_f32_16x16x32_bf16(a1, b01, acc0, 0, 0, 0);
        acc1 = __builtin_amdgcn_mfma_f32_16x16x32_bf16(a0, b10, acc1, 0, 0, 0);
        acc1 = __builtin_amdgcn_mfma_f32_16x16x32_bf16(a1, b11, acc1, 0, 0, 0);
        pf0 = nf0; pf1 = nf1;
        p ^= 1;
    }

    // ---- epilogue: atomic accumulate this h-partial into out ----
    {
        float* ob = out + ((size_t)b * C_CH + wid * 16 + ((lane >> 4) << 2)) * OUT_LEN
                        + tau0 + (lane & 15);
        #pragma unroll
        for (int r = 0; r < 4; ++r) {
            unsafeAtomicAdd(&ob[(size_t)r * OUT_LEN],      acc0[r]);
            unsafeAtomicAdd(&ob[(size_t)r * OUT_LEN + 16], acc1[r]);
        }
    }
}

// ---------------------------------------------------------------------------
// Monolithic fallback (round-1, known-correct) if ws too small.
// ---------------------------------------------------------------------------
__global__ __launch_bounds__(256) void spectral_pool_mono(
    const float* __restrict__ x, const int* __restrict__ length,
    float* __restrict__ out)
{
    const int bc  = blockIdx.x;
    const int b   = bc >> 6;
    const int tid = threadIdx.x;
    const int L   = length[b];

    const float* __restrict__ xrow = x + (size_t)bc * T_IN;
    float* __restrict__ orow = out + (size_t)bc * OUT_LEN;

    if (L < OUT_LEN) {
        for (int t = tid; t < OUT_LEN; t += 256)
            orow[t] = (t < L) ? xrow[t] : 0.0f;
        return;
    }

    __shared__ float xs[T_IN];
    __shared__ float Xr[257];
    __shared__ float Xi[257];
    __shared__ float red[256];

    {
        const float4* __restrict__ src = (const float4*)xrow;
        float4* dst = (float4*)xs;
        #pragma unroll
        for (int i = 0; i < T_IN / 4 / 256; ++i)
            dst[tid + i * 256] = src[tid + i * 256];
    }
    __syncthreads();

    const float twoPi = 6.28318530717958647692f;
    const float fL = (float)L;

    {
        const int k = tid;
        float s, co;
        sincosf(-twoPi * (float)k / fL, &s, &co);
        float zr = 1.0f, zi = 0.0f;
        float arr = 0.0f, aii = 0.0f;
        for (int t = 0; t < L; ++t) {
            const float xv = xs[t];
            arr = fmaf(xv, zr, arr);
            aii = fmaf(xv, zi, aii);
            const float nzr = fmaf(zr, co, -zi * s);
            const float nzi = fmaf(zr, s,   zi * co);
            zr = nzr; zi = nzi;
        }
        Xr[k] = arr;
        Xi[k] = aii;
    }
    {
        float part = 0.0f;
        for (int t = tid; t < L; t += 256) {
            const int m = (256 * t) % L;
            part = fmaf(xs[t], cosf(-twoPi * (float)m / fL), part);
        }
        red[tid] = part;
    }
    __syncthreads();
    #pragma unroll
    for (int sft = 128; sft > 0; sft >>= 1) {
        if (tid < sft) red[tid] += red[tid + sft];
        __syncthreads();
    }
    if (tid == 0) { Xr[256] = red[0]; Xi[256] = 0.0f; }
    __syncthreads();
    {
        const int t = tid;
        float s, co;
        sincosf(twoPi * (float)t / 512.0f, &s, &co);
        float zr = co, zi = s;
        float accE = 0.0f, accO = 0.0f;
        #pragma unroll 2
        for (int k = 1; k < 256; ++k) {
            const float re = fmaf(Xr[k], zr, -Xi[k] * zi);
            if (k & 1) accO += re; else accE += re;
            const float nzr = fmaf(zr, co, -zi * s);
            const float nzi = fmaf(zr, s,   zi * co);
            zr = nzr; zi = nzi;
        }
        const float base = Xr[0] + ((t & 1) ? -Xr[256] : Xr[256]);
        const float invN = 1.0f / 512.0f;
        orow[t]       = (base + 2.0f * (accE + accO)) * invN;
        orow[t + 256] = (base + 2.0f * (accE - accO)) * invN;
    }
}

extern "C" void kernel_launch(void* const* d_in, const int* in_sizes, int n_in,
                              void* d_out, int out_size, void* d_ws, size_t ws_size,
                              hipStream_t stream) {
    const float* x      = (const float*)d_in[0];
    const int*   length = (const int*)d_in[1];
    float*       out    = (float*)d_out;
    const int B = in_sizes[1];

    const size_t xbf_bytes = (size_t)B * C_CH * T_IN * 2;   // 4 MB

    if (ws_size >= xbf_bytes) {
        unsigned short* xbf = (unsigned short*)d_ws;
        const int total8 = B * C_CH * T_IN / 8;
        hipLaunchKernelGGL(prep_kernel, dim3((total8 + 255) / 256), dim3(256),
                           0, stream, x, length, xbf, out, B);
        hipLaunchKernelGGL(spectral_gemm, dim3(B * NTT * KSPLIT), dim3(256),
                           0, stream, xbf, length, out, B);
    } else {
        hipLaunchKernelGGL(spectral_pool_mono, dim3(B * C_CH), dim3(256), 0, stream,
                           x, length, out);
    }
}

// Round 13
// 18.167 us; speedup vs baseline: 1.2721x; 1.2721x over previous
//
#include <hip/hip_runtime.h>
#include <hip/hip_bf16.h>
#include <math.h>

#define OUT_LEN 512
#define T_IN    2048
#define C_CH    64
#define BN      32
#define NTT     (OUT_LEN / BN)   // 16 tau-tiles
#define KSPLIT  4

typedef __attribute__((ext_vector_type(8))) short bf16x8;
typedef __attribute__((ext_vector_type(4))) float f32x4;

static __device__ __forceinline__ short f2bf(float f) {
    unsigned int u = __float_as_uint(f);
    unsigned int r = (u + 0x7FFFu + ((u >> 16) & 1u)) >> 16;   // RNE
    return (short)r;
}

// ---------------------------------------------------------------------------
// K0: fused prep.
//  - convert x (f32) -> xbf (bf16) for LONG batches only (short never read)
//  - init out: zeros for L>=512 batches (atomic base), masked copy for L<512
// ---------------------------------------------------------------------------
__global__ __launch_bounds__(256) void prep_kernel(
    const float* __restrict__ x, const int* __restrict__ length,
    unsigned short* __restrict__ xbf, float* __restrict__ out, int B)
{
    const int idx = blockIdx.x * 256 + threadIdx.x;
    const int total8 = B * C_CH * T_IN / 8;
    if (idx < total8) {
        const int bb = idx >> 14;                   // 16384 granules per batch
        if (length[bb] >= OUT_LEN) {
            const float4 v0 = ((const float4*)x)[2 * idx];
            const float4 v1 = ((const float4*)x)[2 * idx + 1];
            union { short s[8]; int4 v; } pk;
            pk.s[0] = f2bf(v0.x); pk.s[1] = f2bf(v0.y);
            pk.s[2] = f2bf(v0.z); pk.s[3] = f2bf(v0.w);
            pk.s[4] = f2bf(v1.x); pk.s[5] = f2bf(v1.y);
            pk.s[6] = f2bf(v1.z); pk.s[7] = f2bf(v1.w);
            ((int4*)xbf)[idx] = pk.v;
        }
    }
    const int outq = B * C_CH * (OUT_LEN / 4);
    if (idx < outq) {
        const int b = idx >> 13;                    // 8192 float4 per batch
        const int L = length[b];
        float4 o = {0.f, 0.f, 0.f, 0.f};
        if (L < OUT_LEN) {
            const int t4 = idx & (OUT_LEN / 4 - 1);
            const int c  = (idx >> 7) & (C_CH - 1);
            const int t  = t4 * 4;
            const float4 v = *(const float4*)(x + ((size_t)b * C_CH + c) * T_IN + t);
            o.x = (t + 0 < L) ? v.x : 0.0f;
            o.y = (t + 1 < L) ? v.y : 0.0f;
            o.z = (t + 2 < L) ? v.z : 0.0f;
            o.w = (t + 3 < L) ? v.w : 0.0f;
        }
        ((float4*)out)[idx] = o;
    }
}

// ---------------------------------------------------------------------------
// K1: GEMM with on-the-fly M, atomic accumulation into out (r6 structure).
// M_L[t][tau] = sin(pi*n/L) * cot(pi*n/(512L)) / 512,  n = 512t - tau*L.
// sin term: (-1)^tau * tab[t]; sign folds into cot's argument.
// cot(w) ~ 1/w + w*(-1/3 - w^2/45 - 2w^4/945) after wrap w -= pi*rndne(w/pi).
// A-fragments in registers; B double-buffered in LDS, ONE barrier per iter.
// Grid: bid = (b*NTT + tt)*4 + h (r6 order, best measured). 1024 blocks.
// ---------------------------------------------------------------------------
__global__ __launch_bounds__(256) void spectral_gemm(
    const unsigned short* __restrict__ xbf, const int* __restrict__ length,
    float* __restrict__ out, int B)
{
    const int bid = blockIdx.x;
    const int h   = bid & (KSPLIT - 1);
    const int rem = bid >> 2;
    const int tt  = rem % NTT;
    const int b   = rem / NTT;
    const int tid = threadIdx.x;
    const int L   = length[b];
    if (L < OUT_LEN) return;                        // prep wrote the copy branch

    const int tau0 = tt * BN;
    const int nc   = (L + 63) >> 6;                 // 8..32
    const int tmax = nc << 6;                       // highest tab index read +1

    __shared__ short B_lds[2][2][2][64][8];         // [p][j][ksub][lane][i]
    __shared__ float tab[T_IN];

    // ---- tab[t] = sin(2*pi*(256t mod L)/L)/512 for t<L, 0 for L<=t<tmax ----
    {
        const float invLf = 1.0f / (float)L;
        int q = (int)(65536.0f * invLf);
        int d256 = 65536 - q * L;                   // 65536 mod L
        if (d256 < 0)  d256 += L;
        if (d256 >= L) d256 -= L;
        const int v = tid << 8;                     // 256*tid
        q = (int)((float)v * invLf);
        int m = v - q * L;
        if (m < 0)  m += L;
        if (m >= L) m -= L;
        for (int i = tid; i < tmax; i += 256) {     // only the region BUILD reads
            tab[i] = (i < L)
                ? __builtin_amdgcn_sinf((float)m * invLf) * 0.001953125f : 0.0f;
            m += d256; if (m >= L) m -= L;
        }
    }

    // ---- A role: global fragment pointer (regs == fragment, no LDS) ----
    const int lane = tid & 63;
    const int wid  = tid >> 6;
    const unsigned short* gsrc =
        xbf + ((size_t)(b * C_CH + wid * 16 + (lane & 15))) * T_IN + ((lane >> 4) * 8);

    // ---- B-build role ----
    const int tau_l = tid & 31;
    const int tauv  = tau0 + tau_l;
    const int tb8   = (tid >> 5) << 3;              // 0,8,...,56
    const int jB    = tau_l >> 4;
    const int gB    = (tb8 >> 3) & 3;
    const int ksubB = tb8 >> 5;
    const int laneB = (tau_l & 15) + (gB << 4);

    const int L256 = L << 8;
    const int L512 = L << 9;
    const float inv512L   = 1.0f / (float)L512;
    const float piInv512L = 3.14159265358979f * inv512L;
    const int sgn = (tauv & 1) ? -1 : 1;
    const int dnc = sgn * (KSPLIT * 64 * 512);      // chunk advance (t += 256)
    const float stpf = (float)(sgn << 9);           // +-512 per t

    // initial n0 = sgn*(512*t_first - tau*L), reduced mod 512L to (-256L, 256L]
    int n0 = sgn * (512 * (h * 64 + tb8) - tauv * L);
    {
        const int q = (int)rintf((float)n0 * inv512L);
        n0 -= q * L512;
        if (n0 <= -L256) n0 += L512;
        if (n0 >   L256) n0 -= L512;
    }

    f32x4 acc0 = {0.f, 0.f, 0.f, 0.f};
    f32x4 acc1 = {0.f, 0.f, 0.f, 0.f};

    // prologue A prefetch (issue before tab barrier to hide HBM latency)
    int4 pf0, pf1;
    {
        const unsigned short* g = gsrc + (h << 6);
        pf0 = *(const int4*)(g);
        pf1 = *(const int4*)(g + 32);
    }

    // M-chunk builder: 8 entries/thread into B_lds[pp], advances n0.
    auto BUILD = [&](int pp, int ss) {
        const int t0 = ss << 6;
        float sv0[4], sv1[4];
        *(float4*)sv0 = *(const float4*)&tab[t0 + tb8];       // broadcast b128
        *(float4*)sv1 = *(const float4*)&tab[t0 + tb8 + 4];
        const float n0f = (float)n0;                          // exact (<2^21)
        float Mv[8];
        #pragma unroll
        for (int d = 0; d < 8; ++d) {
            const float nf = fmaf((float)d, stpf, n0f);       // exact
            const float w  = nf * piInv512L;
            const float rW = rintf(w * 0.318309886183790672f);
            const float wp = fmaf(rW, -3.14159265358979f, w); // wrap to (-pi/2,pi/2]
            const float ru = __builtin_amdgcn_rcpf(wp);
            const float w2 = wp * wp;
            const float pq = fmaf(w2, fmaf(w2, -2.1164021e-3f, -2.2222222e-2f),
                                  -0.333333333f);
            const float cotv = fmaf(wp, pq, ru);
            Mv[d] = ((d < 4) ? sv0[d] : sv1[d - 4]) * cotv;
        }
        // rare singular fix: n hits 0 inside this chunk -> true M is 1 (t<L)
        const int negAn = (sgn > 0) ? -n0 : n0;
        if ((unsigned)negAn <= 3584u && (n0 & 511) == 0) {
            const int ds = negAn >> 9;
            const float fix = (t0 + tb8 + ds < L) ? 1.0f : 0.0f;
            #pragma unroll
            for (int d = 0; d < 8; ++d)                        // static idx only
                if (d == ds) Mv[d] = fix;
        }
        union { __hip_bfloat162 h2[4]; int4 v; } pk;
        #pragma unroll
        for (int e = 0; e < 4; ++e)
            pk.h2[e] = __float22bfloat162_rn(make_float2(Mv[2 * e], Mv[2 * e + 1]));
        *(int4*)&B_lds[pp][jB][ksubB][laneB][0] = pk.v;
        n0 += dnc;
        if (n0 >  L256)  n0 -= L512;
        if (n0 <= -L256) n0 += L512;
    };

    __syncthreads();                                // tab visible
    BUILD(0, h);
    int p = 0;

    for (int s = h; s < nc; s += KSPLIT) {
        __syncthreads();                            // publishes B_lds[p]
        const int sn = s + KSPLIT;
        const bool more = (sn < nc);
        int4 nf0 = pf0, nf1 = pf1;
        if (more) {
            const unsigned short* g = gsrc + (sn << 6);
            nf0 = *(const int4*)(g);
            nf1 = *(const int4*)(g + 32);
        }
        const bf16x8 b00 = *(const bf16x8*)&B_lds[p][0][0][lane][0];
        const bf16x8 b01 = *(const bf16x8*)&B_lds[p][0][1][lane][0];
        const bf16x8 b10 = *(const bf16x8*)&B_lds[p][1][0][lane][0];
        const bf16x8 b11 = *(const bf16x8*)&B_lds[p][1][1][lane][0];
        if (more) BUILD(p ^ 1, sn);                 // overlaps MFMA across waves
        const bf16x8 a0 = *(const bf16x8*)&pf0;
        const bf16x8 a1 = *(const bf16x8*)&pf1;
        acc0 = __builtin_amdgcn_mfma_f32_16x16x32_bf16(a0, b00, acc0, 0, 0, 0);
        acc0 = __builtin_amdgcn_mfma_f32_16x16x32_bf16(a1, b01, acc0, 0, 0, 0);
        acc1 = __builtin_amdgcn_mfma_f32_16x16x32_bf16(a0, b10, acc1, 0, 0, 0);
        acc1 = __builtin_amdgcn_mfma_f32_16x16x32_bf16(a1, b11, acc1, 0, 0, 0);
        pf0 = nf0; pf1 = nf1;
        p ^= 1;
    }

    // ---- epilogue: atomic accumulate this h-partial into out ----
    {
        float* ob = out + ((size_t)b * C_CH + wid * 16 + ((lane >> 4) << 2)) * OUT_LEN
                        + tau0 + (lane & 15);
        #pragma unroll
        for (int r = 0; r < 4; ++r) {
            unsafeAtomicAdd(&ob[(size_t)r * OUT_LEN],      acc0[r]);
            unsafeAtomicAdd(&ob[(size_t)r * OUT_LEN + 16], acc1[r]);
        }
    }
}

// ---------------------------------------------------------------------------
// Monolithic fallback (round-1, known-correct) if ws too small.
// ---------------------------------------------------------------------------
__global__ __launch_bounds__(256) void spectral_pool_mono(
    const float* __restrict__ x, const int* __restrict__ length,
    float* __restrict__ out)
{
    const int bc  = blockIdx.x;
    const int b   = bc >> 6;
    const int tid = threadIdx.x;
    const int L   = length[b];

    const float* __restrict__ xrow = x + (size_t)bc * T_IN;
    float* __restrict__ orow = out + (size_t)bc * OUT_LEN;

    if (L < OUT_LEN) {
        for (int t = tid; t < OUT_LEN; t += 256)
            orow[t] = (t < L) ? xrow[t] : 0.0f;
        return;
    }

    __shared__ float xs[T_IN];
    __shared__ float Xr[257];
    __shared__ float Xi[257];
    __shared__ float red[256];

    {
        const float4* __restrict__ src = (const float4*)xrow;
        float4* dst = (float4*)xs;
        #pragma unroll
        for (int i = 0; i < T_IN / 4 / 256; ++i)
            dst[tid + i * 256] = src[tid + i * 256];
    }
    __syncthreads();

    const float twoPi = 6.28318530717958647692f;
    const float fL = (float)L;

    {
        const int k = tid;
        float s, co;
        sincosf(-twoPi * (float)k / fL, &s, &co);
        float zr = 1.0f, zi = 0.0f;
        float arr = 0.0f, aii = 0.0f;
        for (int t = 0; t < L; ++t) {
            const float xv = xs[t];
            arr = fmaf(xv, zr, arr);
            aii = fmaf(xv, zi, aii);
            const float nzr = fmaf(zr, co, -zi * s);
            const float nzi = fmaf(zr, s,   zi * co);
            zr = nzr; zi = nzi;
        }
        Xr[k] = arr;
        Xi[k] = aii;
    }
    {
        float part = 0.0f;
        for (int t = tid; t < L; t += 256) {
            const int m = (256 * t) % L;
            part = fmaf(xs[t], cosf(-twoPi * (float)m / fL), part);
        }
        red[tid] = part;
    }
    __syncthreads();
    #pragma unroll
    for (int sft = 128; sft > 0; sft >>= 1) {
        if (tid < sft) red[tid] += red[tid + sft];
        __syncthreads();
    }
    if (tid == 0) { Xr[256] = red[0]; Xi[256] = 0.0f; }
    __syncthreads();
    {
        const int t = tid;
        float s, co;
        sincosf(twoPi * (float)t / 512.0f, &s, &co);
        float zr = co, zi = s;
        float accE = 0.0f, accO = 0.0f;
        #pragma unroll 2
        for (int k = 1; k < 256; ++k) {
            const float re = fmaf(Xr[k], zr, -Xi[k] * zi);
            if (k & 1) accO += re; else accE += re;
            const float nzr = fmaf(zr, co, -zi * s);
            const float nzi = fmaf(zr, s,   zi * co);
            zr = nzr; zi = nzi;
        }
        const float base = Xr[0] + ((t & 1) ? -Xr[256] : Xr[256]);
        const float invN = 1.0f / 512.0f;
        orow[t]       = (base + 2.0f * (accE + accO)) * invN;
        orow[t + 256] = (base + 2.0f * (accE - accO)) * invN;
    }
}

extern "C" void kernel_launch(void* const* d_in, const int* in_sizes, int n_in,
                              void* d_out, int out_size, void* d_ws, size_t ws_size,
                              hipStream_t stream) {
    const float* x      = (const float*)d_in[0];
    const int*   length = (const int*)d_in[1];
    float*       out    = (float*)d_out;
    const int B = in_sizes[1];

    const size_t xbf_bytes = (size_t)B * C_CH * T_IN * 2;   // 4 MB

    if (ws_size >= xbf_bytes) {
        unsigned short* xbf = (unsigned short*)d_ws;
        const int total8 = B * C_CH * T_IN / 8;
        hipLaunchKernelGGL(prep_kernel, dim3((total8 + 255) / 256), dim3(256),
                           0, stream, x, length, xbf, out, B);
        hipLaunchKernelGGL(spectral_gemm, dim3(B * NTT * KSPLIT), dim3(256),
                           0, stream, xbf, length, out, B);
    } else {
        hipLaunchKernelGGL(spectral_pool_mono, dim3(B * C_CH), dim3(256), 0, stream,
                           x, length, out);
    }
}